// Round 2
// baseline (141.508 us; speedup 1.0000x reference)
//
#include <hip/hip_runtime.h>
#include <math.h>

#define B_ 8
#define L_ 200
#define H_ 128
#define NH_ 2
#define HD_ 64
#define LP_ 256   // padded L for float4 score loads
#define TV_ 32    // time vocab

// ---------------------------------------------------------------- zero Kt pad
__global__ void zero_kt_kernel(float* __restrict__ kt){
    kt[blockIdx.x * 256 + threadIdx.x] = 0.f;   // grid covers B*NH*HD*LP
}

// ---------------------------------------------------------------- fused QKV
// blockIdx.x = row (b*L+l) 0..1599, blockIdx.y = m (0:Q,1:K,2:V), 128 threads
__global__ __launch_bounds__(128)
void qkv_kernel(const float* __restrict__ X,
                const float* __restrict__ Wq, const float* __restrict__ bq,
                const float* __restrict__ Wk, const float* __restrict__ bk,
                const float* __restrict__ Wv, const float* __restrict__ bv,
                const float* __restrict__ kpt, const float* __restrict__ vpt,
                float* __restrict__ Q, float* __restrict__ Kt, float* __restrict__ Vp){
    const int row = blockIdx.x;
    const int m   = blockIdx.y;
    const int j   = threadIdx.x;
    const int b   = row / L_, l = row % L_;
    __shared__ float xs[H_];
    xs[j] = X[row * H_ + j];
    __syncthreads();
    const float* W = (m == 0) ? Wq : ((m == 1) ? Wk : Wv);
    float acc = 0.f;
    #pragma unroll 8
    for (int i = 0; i < H_; ++i) acc += xs[i] * W[i * H_ + j];
    const int h = j >> 6, d = j & 63;
    if (m == 0) {
        Q[row * H_ + j] = acc + bq[j];
    } else if (m == 1) {
        float v = acc + bk[j] + kpt[l * H_ + j];
        Kt[(((b * NH_ + h) * HD_) + d) * LP_ + l] = v;          // [b,h,d,k]
    } else {
        float v = acc + bv[j] + vpt[l * H_ + j];
        Vp[(((b * NH_ + h) * L_) + l) * HD_ + d] = v;           // [b,h,k,d]
    }
}

// ---------------------------------------------------------------- attention
// 1 wave per (b,h,q); 4 waves/block; grid = B*NH*L/4 = 800
__global__ __launch_bounds__(256)
void attn_kernel(const float* __restrict__ Q, const float* __restrict__ Kt,
                 const float* __restrict__ Vp, const int* __restrict__ tseq,
                 const float* __restrict__ mask,
                 const float* __restrict__ ktt, const float* __restrict__ vtt,
                 float* __restrict__ ctx){
    const int wave = threadIdx.x >> 6, lane = threadIdx.x & 63;
    const int gq = blockIdx.x * 4 + wave;        // (b*NH+h)*L + q
    const int q  = gq % L_;
    const int bh = gq / L_;
    const int h  = bh % NH_, b = bh / NH_;

    __shared__ __align__(16) float qs [4][HD_];
    __shared__            float qkt[4][TV_];
    __shared__            float ss [4][TV_];
    __shared__ __align__(16) float ps [4][LP_];

    qs[wave][lane] = Q[(b * L_ + q) * H_ + h * HD_ + lane];
    if (lane < TV_) ss[wave][lane] = 0.f;
    __syncthreads();

    // qkt[i] = dot(q, key_time_table[i, head slice])
    if (lane < TV_) {
        float a = 0.f;
        #pragma unroll 8
        for (int d = 0; d < HD_; ++d) a += qs[wave][d] * ktt[lane * H_ + h * HD_ + d];
        qkt[wave][lane] = a;
    }
    __syncthreads();

    const int tq = tseq[b * L_ + q];

    // ---- phase A: lane handles k = 4*lane .. 4*lane+3
    const float4* kt4 = (const float4*)(Kt + (size_t)bh * HD_ * LP_);
    float4 s4 = make_float4(0.f, 0.f, 0.f, 0.f);
    #pragma unroll 4
    for (int d = 0; d < HD_; ++d) {
        const float qd = qs[wave][d];
        const float4 kv = kt4[d * (LP_ / 4) + lane];
        s4.x += qd * kv.x; s4.y += qd * kv.y; s4.z += qd * kv.z; s4.w += qd * kv.w;
    }
    float sv[4] = {s4.x, s4.y, s4.z, s4.w};
    const int k0 = lane * 4;
    float mx = -INFINITY;
    #pragma unroll
    for (int jj = 0; jj < 4; ++jj) {
        const int k = k0 + jj;
        if (k < L_) {
            int dt = tq - tseq[b * L_ + k]; if (dt < 0) dt = -dt;
            int idx = (int)log1pf((float)dt);
            if (idx > TV_ - 1) idx = TV_ - 1;
            float s = (sv[jj] + qkt[wave][idx]) * 0.125f
                      + mask[((size_t)b * L_ + q) * L_ + k];
            sv[jj] = s;
            atomicAdd(&ss[wave][idx], s);      // pre-softmax bucket sums
            if (s > mx) mx = s;
        } else sv[jj] = -INFINITY;
    }
    // wave-wide softmax
    for (int off = 32; off; off >>= 1) { float o = __shfl_xor(mx, off); if (o > mx) mx = o; }
    float sum = 0.f, ev[4];
    #pragma unroll
    for (int jj = 0; jj < 4; ++jj) {
        float e = (k0 + jj < L_) ? __expf(sv[jj] - mx) : 0.f;
        ev[jj] = e; sum += e;
    }
    for (int off = 32; off; off >>= 1) sum += __shfl_xor(sum, off);
    ((float4*)ps[wave])[lane] = make_float4(ev[0], ev[1], ev[2], ev[3]);
    __syncthreads();

    // ---- phase B: lane = d
    const float inv = 1.f / sum;
    const float* vp = Vp + (size_t)bh * L_ * HD_;
    float c = 0.f;
    #pragma unroll 4
    for (int k = 0; k < L_; ++k) c += ps[wave][k] * vp[k * HD_ + lane];
    c *= inv;
    float tc = 0.f;
    #pragma unroll 8
    for (int i = 0; i < TV_; ++i) tc += ss[wave][i] * vtt[i * H_ + h * HD_ + lane];
    ctx[((size_t)b * L_ + q) * H_ + h * HD_ + lane] = c + tc;
}

// ---------------------------------------------------------------- out proj + LN
__global__ __launch_bounds__(128)
void out_kernel(const float* __restrict__ ctx, const float* __restrict__ Wd,
                const float* __restrict__ bd, const float* __restrict__ X,
                const float* __restrict__ g, const float* __restrict__ bb,
                float* __restrict__ out){
    const int row = blockIdx.x, j = threadIdx.x;
    __shared__ float cs[H_];
    __shared__ float red[4];
    cs[j] = ctx[row * H_ + j];
    __syncthreads();
    float acc = 0.f;
    #pragma unroll 8
    for (int i = 0; i < H_; ++i) acc += cs[i] * Wd[i * H_ + j];
    const float x = acc + bd[j] + X[row * H_ + j];

    const int wave = j >> 6, lane = j & 63;
    float s = x;
    for (int off = 32; off; off >>= 1) s += __shfl_xor(s, off);
    if (lane == 0) red[wave] = s;
    __syncthreads();
    const float mean = (red[0] + red[1]) * (1.f / H_);
    const float dx = x - mean;
    float s2 = dx * dx;
    for (int off = 32; off; off >>= 1) s2 += __shfl_xor(s2, off);
    if (lane == 0) red[wave + 2] = s2;
    __syncthreads();
    const float var = (red[2] + red[3]) * (1.f / H_);
    const float y = dx * rsqrtf(var + 1e-12f) * g[j] + bb[j];
    out[row * H_ + j] = y;
}

// ---------------------------------------------------------------- launch
extern "C" void kernel_launch(void* const* d_in, const int* in_sizes, int n_in,
                              void* d_out, int out_size, void* d_ws, size_t ws_size,
                              hipStream_t stream) {
    const float* X    = (const float*)d_in[0];
    const int*   tseq = (const int*)  d_in[1];
    const float* mask = (const float*)d_in[2];
    const float* Wq = (const float*)d_in[3],  *bq = (const float*)d_in[4];
    const float* Wk = (const float*)d_in[5],  *bk = (const float*)d_in[6];
    const float* Wv = (const float*)d_in[7],  *bv = (const float*)d_in[8];
    const float* Wd = (const float*)d_in[9],  *bd = (const float*)d_in[10];
    const float* g  = (const float*)d_in[11], *bb = (const float*)d_in[12];
    const float* ktt = (const float*)d_in[13], *vtt = (const float*)d_in[14];
    const float* kpt = (const float*)d_in[15], *vpt = (const float*)d_in[16];

    float* ws  = (float*)d_ws;
    float* Q   = ws;                          // B*L*H      = 204800
    float* Kt  = Q   + B_ * L_ * H_;          // B*NH*HD*LP = 262144
    float* Vp  = Kt  + B_ * NH_ * HD_ * LP_;  // B*L*H      = 204800
    float* ctx = Vp  + B_ * L_ * H_;          // B*L*H      = 204800

    zero_kt_kernel<<<B_ * NH_ * HD_ * LP_ / 256, 256, 0, stream>>>(Kt);
    dim3 g1(B_ * L_, 3);
    qkv_kernel<<<g1, 128, 0, stream>>>(X, Wq, bq, Wk, bk, Wv, bv, kpt, vpt, Q, Kt, Vp);
    attn_kernel<<<B_ * NH_ * L_ / 4, 256, 0, stream>>>(Q, Kt, Vp, tseq, mask, ktt, vtt, ctx);
    out_kernel<<<B_ * L_, 128, 0, stream>>>(ctx, Wd, bd, X, g, bb, (float*)d_out);
}

// Round 3
// 140.717 us; speedup vs baseline: 1.0056x; 1.0056x over previous
//
#include <hip/hip_runtime.h>
#include <math.h>

#define B_ 8
#define L_ 200
#define H_ 128
#define NH_ 2
#define HD_ 64
#define LP_ 256   // padded L (pad region never zeroed; OOB contributions discarded)
#define TV_ 32    // time vocab
#define RQ_ 8     // rows per qkv block
#define TQ_ 4     // q rows per attn block

// ---------------------------------------------------------------- fused QKV
// grid (B*L/RQ_, 3), 128 threads; m = 0:Q, 1:K(transposed), 2:V
__global__ __launch_bounds__(128)
void qkv_kernel(const float* __restrict__ X,
                const float* __restrict__ Wq, const float* __restrict__ bq,
                const float* __restrict__ Wk, const float* __restrict__ bk,
                const float* __restrict__ Wv, const float* __restrict__ bv,
                const float* __restrict__ kpt, const float* __restrict__ vpt,
                float* __restrict__ Q, float* __restrict__ Kt, float* __restrict__ Vp){
    const int r0 = blockIdx.x * RQ_;
    const int m  = blockIdx.y;
    const int j  = threadIdx.x;
    __shared__ float xs[RQ_][H_];
    #pragma unroll
    for (int r = 0; r < RQ_; ++r) xs[r][j] = X[(r0 + r) * H_ + j];
    __syncthreads();
    const float* W = (m == 0) ? Wq : ((m == 1) ? Wk : Wv);
    float acc[RQ_];
    #pragma unroll
    for (int r = 0; r < RQ_; ++r) acc[r] = 0.f;
    #pragma unroll 4
    for (int i = 0; i < H_; ++i) {
        const float w = W[i * H_ + j];
        #pragma unroll
        for (int r = 0; r < RQ_; ++r) acc[r] += xs[r][i] * w;
    }
    const int h = j >> 6, d = j & 63;
    if (m == 0) {
        const float bj = bq[j];
        #pragma unroll
        for (int r = 0; r < RQ_; ++r) Q[(r0 + r) * H_ + j] = acc[r] + bj;
    } else if (m == 1) {
        const float bj = bk[j];
        #pragma unroll
        for (int r = 0; r < RQ_; ++r) {
            const int row = r0 + r, b = row / L_, l = row % L_;
            Kt[((b * NH_ + h) * HD_ + d) * LP_ + l] = acc[r] + bj + kpt[l * H_ + j];
        }
    } else {
        const float bj = bv[j];
        #pragma unroll
        for (int r = 0; r < RQ_; ++r) {
            const int row = r0 + r, b = row / L_, l = row % L_;
            Vp[((b * NH_ + h) * L_ + l) * HD_ + d] = acc[r] + bj + vpt[l * H_ + j];
        }
    }
}

// ------------------------------------------- fused attention + out-proj + LN
// grid = B * (L/TQ_) blocks of 512 threads (8 waves).
// wave w: head h = w&1, q-row qr = w>>1. After ctx in LDS: Wd GEMV + LN.
__global__ __launch_bounds__(512)
void attn_out_kernel(const float* __restrict__ Q, const float* __restrict__ Kt,
                     const float* __restrict__ Vp, const int* __restrict__ tseq,
                     const float* __restrict__ mask,
                     const float* __restrict__ ktt, const float* __restrict__ vtt,
                     const float* __restrict__ Wd, const float* __restrict__ bd,
                     const float* __restrict__ X, const float* __restrict__ g,
                     const float* __restrict__ bb, float* __restrict__ out){
    const int b  = blockIdx.x / (L_ / TQ_);
    const int q0 = (blockIdx.x % (L_ / TQ_)) * TQ_;
    const int w  = threadIdx.x >> 6, lane = threadIdx.x & 63;
    const int h  = w & 1, qr = w >> 1, q = q0 + qr;
    const int bh = b * NH_ + h;

    __shared__ __align__(16) float qs [8][HD_];
    __shared__ float qkt[8][TV_];
    __shared__ float ss [8][TV_];
    __shared__ __align__(16) float ps [8][LP_];
    __shared__ float ctx_s[TQ_][H_];
    __shared__ float red1[8], red2[8];

    // per-wave LDS (same-wave write->read, no barrier needed)
    qs[w][lane] = Q[(b * L_ + q) * H_ + h * HD_ + lane];
    if (lane < TV_) ss[w][lane] = 0.f;
    if (lane < TV_) {
        float a = 0.f;
        #pragma unroll 8
        for (int d = 0; d < HD_; ++d) a += qs[w][d] * ktt[lane * H_ + h * HD_ + d];
        qkt[w][lane] = a;
    }

    // ---- phase A: lane handles k = 4*lane .. 4*lane+3
    const float4* kt4 = (const float4*)(Kt + (size_t)bh * HD_ * LP_);
    float4 s4 = make_float4(0.f, 0.f, 0.f, 0.f);
    #pragma unroll 4
    for (int d = 0; d < HD_; ++d) {
        const float qd = qs[w][d];
        const float4 kv = kt4[d * (LP_ / 4) + lane];
        s4.x += qd * kv.x; s4.y += qd * kv.y; s4.z += qd * kv.z; s4.w += qd * kv.w;
    }
    float sv[4] = {s4.x, s4.y, s4.z, s4.w};
    const int k0 = lane * 4;
    float mx = -INFINITY;
    if (k0 < L_) {  // lanes 0..49 (L_/4 = 50): rows are 800B-aligned -> float4/int4 ok
        const float4 m4 = ((const float4*)(mask + ((size_t)(b * L_ + q)) * L_))[lane];
        const int4   t4 = ((const int4*)(tseq + b * L_))[lane];
        const int    tq = tseq[b * L_ + q];
        const float mv[4] = {m4.x, m4.y, m4.z, m4.w};
        const int   tk[4] = {t4.x, t4.y, t4.z, t4.w};
        #pragma unroll
        for (int jj = 0; jj < 4; ++jj) {
            int dt = tq - tk[jj]; if (dt < 0) dt = -dt;
            int idx = (int)log1pf((float)dt);
            if (idx > TV_ - 1) idx = TV_ - 1;
            float s = (sv[jj] + qkt[w][idx]) * 0.125f + mv[jj];
            sv[jj] = s;
            atomicAdd(&ss[w][idx], s);          // pre-softmax bucket sums
            if (s > mx) mx = s;
        }
    } else {
        sv[0] = sv[1] = sv[2] = sv[3] = -INFINITY;
    }
    // wave-wide softmax
    for (int off = 32; off; off >>= 1) { float o = __shfl_xor(mx, off); if (o > mx) mx = o; }
    float sum = 0.f, ev[4];
    #pragma unroll
    for (int jj = 0; jj < 4; ++jj) {
        float e = (k0 + jj < L_) ? __expf(sv[jj] - mx) : 0.f;
        ev[jj] = e; sum += e;
    }
    for (int off = 32; off; off >>= 1) sum += __shfl_xor(sum, off);
    ((float4*)ps[w])[lane] = make_float4(ev[0], ev[1], ev[2], ev[3]);

    // ---- phase B: lane = d (ps/ss are same-wave LDS, ordered)
    const float inv = 1.f / sum;
    const float* vp = Vp + (size_t)bh * L_ * HD_;
    float c = 0.f;
    #pragma unroll 4
    for (int k = 0; k < L_; ++k) c += ps[w][k] * vp[k * HD_ + lane];
    c *= inv;
    float tc = 0.f;
    #pragma unroll 8
    for (int i = 0; i < TV_; ++i) tc += ss[w][i] * vtt[i * H_ + h * HD_ + lane];
    ctx_s[qr][h * HD_ + lane] = c + tc;
    __syncthreads();

    // ---- out projection + residual + LayerNorm (4 rows x 128 cols)
    const int r = threadIdx.x >> 7, j = threadIdx.x & 127;
    float acc = 0.f;
    #pragma unroll 8
    for (int i = 0; i < H_; ++i) acc += ctx_s[r][i] * Wd[i * H_ + j];
    const int row = b * L_ + q0 + r;
    const float x = acc + bd[j] + X[row * H_ + j];

    float s = x;
    for (int off = 32; off; off >>= 1) s += __shfl_xor(s, off);
    if (lane == 0) red1[w] = s;
    __syncthreads();
    const float mean = (red1[2 * r] + red1[2 * r + 1]) * (1.f / H_);
    const float dx = x - mean;
    float s2 = dx * dx;
    for (int off = 32; off; off >>= 1) s2 += __shfl_xor(s2, off);
    if (lane == 0) red2[w] = s2;
    __syncthreads();
    const float var = (red2[2 * r] + red2[2 * r + 1]) * (1.f / H_);
    const float y = dx * rsqrtf(var + 1e-12f) * g[j] + bb[j];
    out[row * H_ + j] = y;
}

// ---------------------------------------------------------------- launch
extern "C" void kernel_launch(void* const* d_in, const int* in_sizes, int n_in,
                              void* d_out, int out_size, void* d_ws, size_t ws_size,
                              hipStream_t stream) {
    const float* X    = (const float*)d_in[0];
    const int*   tseq = (const int*)  d_in[1];
    const float* mask = (const float*)d_in[2];
    const float* Wq = (const float*)d_in[3],  *bq = (const float*)d_in[4];
    const float* Wk = (const float*)d_in[5],  *bk = (const float*)d_in[6];
    const float* Wv = (const float*)d_in[7],  *bv = (const float*)d_in[8];
    const float* Wd = (const float*)d_in[9],  *bd = (const float*)d_in[10];
    const float* g  = (const float*)d_in[11], *bb = (const float*)d_in[12];
    const float* ktt = (const float*)d_in[13], *vtt = (const float*)d_in[14];
    const float* kpt = (const float*)d_in[15], *vpt = (const float*)d_in[16];

    float* ws  = (float*)d_ws;
    float* Q   = ws;                          // B*L*H      = 204800
    float* Kt  = Q   + B_ * L_ * H_;          // B*NH*HD*LP = 262144 (pad unzeroed, by design)
    float* Vp  = Kt  + B_ * NH_ * HD_ * LP_;  // B*L*H      = 204800

    dim3 g1(B_ * L_ / RQ_, 3);
    qkv_kernel<<<g1, 128, 0, stream>>>(X, Wq, bq, Wk, bk, Wv, bv, kpt, vpt, Q, Kt, Vp);
    attn_out_kernel<<<B_ * (L_ / TQ_), 512, 0, stream>>>(Q, Kt, Vp, tseq, mask, ktt, vtt,
                                                         Wd, bd, X, g, bb, (float*)d_out);
}

// Round 4
// 121.242 us; speedup vs baseline: 1.1671x; 1.1606x over previous
//
#include <hip/hip_runtime.h>
#include <math.h>

#define B_ 8
#define L_ 200
#define H_ 128
#define NH_ 2
#define HD_ 64
#define LP_ 256   // padded L (pad region never zeroed; OOB contributions discarded)
#define TV_ 32    // time vocab
#define RQ_ 8     // rows per qkv block
#define TQ_ 2     // q rows per attn block

// ---------------------------------------------------------------- fused QKV
// grid (B*L/RQ_, 3), 128 threads; m = 0:Q, 1:K(transposed), 2:V
__global__ __launch_bounds__(128)
void qkv_kernel(const float* __restrict__ X,
                const float* __restrict__ Wq, const float* __restrict__ bq,
                const float* __restrict__ Wk, const float* __restrict__ bk,
                const float* __restrict__ Wv, const float* __restrict__ bv,
                const float* __restrict__ kpt, const float* __restrict__ vpt,
                float* __restrict__ Q, float* __restrict__ Kt, float* __restrict__ Vp){
    const int r0 = blockIdx.x * RQ_;
    const int m  = blockIdx.y;
    const int j  = threadIdx.x;
    __shared__ float xs[RQ_][H_];
    #pragma unroll
    for (int r = 0; r < RQ_; ++r) xs[r][j] = X[(r0 + r) * H_ + j];
    __syncthreads();
    const float* W = (m == 0) ? Wq : ((m == 1) ? Wk : Wv);
    float acc[RQ_];
    #pragma unroll
    for (int r = 0; r < RQ_; ++r) acc[r] = 0.f;
    #pragma unroll 8
    for (int i = 0; i < H_; ++i) {
        const float w = W[i * H_ + j];
        #pragma unroll
        for (int r = 0; r < RQ_; ++r) acc[r] += xs[r][i] * w;
    }
    const int h = j >> 6, d = j & 63;
    if (m == 0) {
        const float bj = bq[j];
        #pragma unroll
        for (int r = 0; r < RQ_; ++r) Q[(r0 + r) * H_ + j] = acc[r] + bj;
    } else if (m == 1) {
        const float bj = bk[j];
        #pragma unroll
        for (int r = 0; r < RQ_; ++r) {
            const int row = r0 + r, b = row / L_, l = row % L_;
            Kt[((b * NH_ + h) * HD_ + d) * LP_ + l] = acc[r] + bj + kpt[l * H_ + j];
        }
    } else {
        const float bj = bv[j];
        #pragma unroll
        for (int r = 0; r < RQ_; ++r) {
            const int row = r0 + r, b = row / L_, l = row % L_;
            Vp[((b * NH_ + h) * L_ + l) * HD_ + d] = acc[r] + bj + vpt[l * H_ + j];
        }
    }
}

// ------------------------------------------- fused attention + out-proj + LN
// grid = B * (L/TQ_) = 800 blocks of 256 threads (4 waves).
// wave w: head h = w&1, q-row qr = w>>1.
__global__ __launch_bounds__(256)
void attn_out_kernel(const float* __restrict__ Q, const float* __restrict__ Kt,
                     const float* __restrict__ Vp, const int* __restrict__ tseq,
                     const float* __restrict__ mask,
                     const float* __restrict__ ktt, const float* __restrict__ vtt,
                     const float* __restrict__ Wd, const float* __restrict__ bd,
                     const float* __restrict__ X, const float* __restrict__ g,
                     const float* __restrict__ bb, float* __restrict__ out){
    const int b  = blockIdx.x / (L_ / TQ_);
    const int q0 = (blockIdx.x % (L_ / TQ_)) * TQ_;
    const int w  = threadIdx.x >> 6, lane = threadIdx.x & 63;
    const int h  = w & 1, qr = w >> 1, q = q0 + qr;
    const int bh = b * NH_ + h;

    __shared__ float ktt_s[TV_][H_ + 1];   // +1 pad: qkt access conflict-free
    __shared__ float vtt_s[TV_][H_ + 1];
    __shared__ __align__(16) float qs [4][HD_];
    __shared__ float qkt[4][TV_];
    __shared__ float ss [4][TV_];
    __shared__ __align__(16) float ps [4][LP_];
    __shared__ float ctx_s[TQ_][H_];
    __shared__ float red1[4], red2[4];

    // coalesced table staging (16 KB x2)
    for (int t = threadIdx.x; t < TV_ * H_; t += 256) {
        ktt_s[t >> 7][t & 127] = ktt[t];
        vtt_s[t >> 7][t & 127] = vtt[t];
    }
    qs[w][lane] = Q[(b * L_ + q) * H_ + h * HD_ + lane];   // per-wave LDS
    if (lane < TV_) ss[w][lane] = 0.f;
    __syncthreads();

    // qkt[i] = dot(q, ktt[i, head slice]); bucket i = lane&31, d-half = lane>>5
    {
        const int i = lane & 31, half = lane >> 5;
        float a = 0.f;
        #pragma unroll 8
        for (int d = 0; d < 32; ++d)
            a += qs[w][half * 32 + d] * ktt_s[i][h * HD_ + half * 32 + d];
        a += __shfl_xor(a, 32);
        if (lane < TV_) qkt[w][lane] = a;
    }

    // ---- phase A: lane handles k = 4*lane .. 4*lane+3
    const float4* kt4 = (const float4*)(Kt + (size_t)bh * HD_ * LP_);
    float4 sA = make_float4(0.f, 0.f, 0.f, 0.f);
    float4 sB = make_float4(0.f, 0.f, 0.f, 0.f);
    #pragma unroll 8
    for (int d = 0; d < HD_; d += 2) {
        const float q0d = qs[w][d], q1d = qs[w][d + 1];
        const float4 k0 = kt4[d * (LP_ / 4) + lane];
        const float4 k1 = kt4[(d + 1) * (LP_ / 4) + lane];
        sA.x += q0d * k0.x; sA.y += q0d * k0.y; sA.z += q0d * k0.z; sA.w += q0d * k0.w;
        sB.x += q1d * k1.x; sB.y += q1d * k1.y; sB.z += q1d * k1.z; sB.w += q1d * k1.w;
    }
    float sv[4] = {sA.x + sB.x, sA.y + sB.y, sA.z + sB.z, sA.w + sB.w};
    const int k0i = lane * 4;
    float mx = -INFINITY;
    if (k0i < L_) {  // lanes 0..49; rows 800B-aligned -> float4/int4 ok
        const float4 m4 = ((const float4*)(mask + ((size_t)(b * L_ + q)) * L_))[lane];
        const int4   t4 = ((const int4*)(tseq + b * L_))[lane];
        const int    tq = tseq[b * L_ + q];
        const float mv[4] = {m4.x, m4.y, m4.z, m4.w};
        const int   tk[4] = {t4.x, t4.y, t4.z, t4.w};
        #pragma unroll
        for (int jj = 0; jj < 4; ++jj) {
            int dt = tq - tk[jj]; if (dt < 0) dt = -dt;
            int idx = (int)log1pf((float)dt);
            if (idx > TV_ - 1) idx = TV_ - 1;
            float s = (sv[jj] + qkt[w][idx]) * 0.125f + mv[jj];
            sv[jj] = s;
            atomicAdd(&ss[w][idx], s);          // pre-softmax bucket sums
            if (s > mx) mx = s;
        }
    } else {
        sv[0] = sv[1] = sv[2] = sv[3] = -INFINITY;
    }
    // wave-wide softmax
    for (int off = 32; off; off >>= 1) { float o = __shfl_xor(mx, off); if (o > mx) mx = o; }
    float sum = 0.f, ev[4];
    #pragma unroll
    for (int jj = 0; jj < 4; ++jj) {
        float e = (k0i + jj < L_) ? __expf(sv[jj] - mx) : 0.f;
        ev[jj] = e; sum += e;
    }
    for (int off = 32; off; off >>= 1) sum += __shfl_xor(sum, off);
    ((float4*)ps[w])[lane] = make_float4(ev[0], ev[1], ev[2], ev[3]);

    // ---- phase B: lane = d (ps/ss same-wave LDS, ordered)
    const float inv = 1.f / sum;
    const float* vp = Vp + (size_t)bh * L_ * HD_;
    float c = 0.f;
    #pragma unroll 8
    for (int k = 0; k < L_; ++k) c += ps[w][k] * vp[k * HD_ + lane];
    c *= inv;
    float tc = 0.f;
    #pragma unroll 8
    for (int i = 0; i < TV_; ++i) tc += ss[w][i] * vtt_s[i][h * HD_ + lane];
    ctx_s[qr][h * HD_ + lane] = c + tc;
    __syncthreads();

    // ---- out projection + residual + LayerNorm (TQ_ rows x 128 cols)
    const int r = threadIdx.x >> 7, j = threadIdx.x & 127;
    float acc = 0.f;
    #pragma unroll 8
    for (int i = 0; i < H_; ++i) acc += ctx_s[r][i] * Wd[i * H_ + j];
    const int row = b * L_ + q0 + r;
    const float x = acc + bd[j] + X[row * H_ + j];

    float s = x;
    for (int off = 32; off; off >>= 1) s += __shfl_xor(s, off);
    if (lane == 0) red1[w] = s;
    __syncthreads();
    const float mean = (red1[2 * r] + red1[2 * r + 1]) * (1.f / H_);
    const float dx = x - mean;
    float s2 = dx * dx;
    for (int off = 32; off; off >>= 1) s2 += __shfl_xor(s2, off);
    if (lane == 0) red2[w] = s2;
    __syncthreads();
    const float var = (red2[2 * r] + red2[2 * r + 1]) * (1.f / H_);
    const float y = dx * rsqrtf(var + 1e-12f) * g[j] + bb[j];
    out[row * H_ + j] = y;
}

// ---------------------------------------------------------------- launch
extern "C" void kernel_launch(void* const* d_in, const int* in_sizes, int n_in,
                              void* d_out, int out_size, void* d_ws, size_t ws_size,
                              hipStream_t stream) {
    const float* X    = (const float*)d_in[0];
    const int*   tseq = (const int*)  d_in[1];
    const float* mask = (const float*)d_in[2];
    const float* Wq = (const float*)d_in[3],  *bq = (const float*)d_in[4];
    const float* Wk = (const float*)d_in[5],  *bk = (const float*)d_in[6];
    const float* Wv = (const float*)d_in[7],  *bv = (const float*)d_in[8];
    const float* Wd = (const float*)d_in[9],  *bd = (const float*)d_in[10];
    const float* g  = (const float*)d_in[11], *bb = (const float*)d_in[12];
    const float* ktt = (const float*)d_in[13], *vtt = (const float*)d_in[14];
    const float* kpt = (const float*)d_in[15], *vpt = (const float*)d_in[16];

    float* ws  = (float*)d_ws;
    float* Q   = ws;                          // B*L*H      = 204800
    float* Kt  = Q   + B_ * L_ * H_;          // B*NH*HD*LP = 262144 (pad unzeroed, by design)
    float* Vp  = Kt  + B_ * NH_ * HD_ * LP_;  // B*L*H      = 204800

    dim3 g1(B_ * L_ / RQ_, 3);
    qkv_kernel<<<g1, 128, 0, stream>>>(X, Wq, bq, Wk, bk, Wv, bv, kpt, vpt, Q, Kt, Vp);
    attn_out_kernel<<<B_ * (L_ / TQ_), 256, 0, stream>>>(Q, Kt, Vp, tseq, mask, ktt, vtt,
                                                         Wd, bd, X, g, bb, (float*)d_out);
}

// Round 5
// 120.754 us; speedup vs baseline: 1.1719x; 1.0040x over previous
//
#include <hip/hip_runtime.h>
#include <math.h>

#define B_ 8
#define L_ 200
#define H_ 128
#define NH_ 2
#define HD_ 64
#define LP_ 256   // padded L (pad region never zeroed; OOB contributions discarded)
#define TV_ 32    // time vocab
#define RQ_ 8     // rows per qkv block

// ---------------------------------------------------------------- fused QKV
// grid (B*L/RQ_, 3), 128 threads; m = 0:Q, 1:K(transposed), 2:V
__global__ __launch_bounds__(128)
void qkv_kernel(const float* __restrict__ X,
                const float* __restrict__ Wq, const float* __restrict__ bq,
                const float* __restrict__ Wk, const float* __restrict__ bk,
                const float* __restrict__ Wv, const float* __restrict__ bv,
                const float* __restrict__ kpt, const float* __restrict__ vpt,
                float* __restrict__ Q, float* __restrict__ Kt, float* __restrict__ Vp){
    const int r0 = blockIdx.x * RQ_;
    const int m  = blockIdx.y;
    const int j  = threadIdx.x;
    __shared__ float xs[RQ_][H_];
    #pragma unroll
    for (int r = 0; r < RQ_; ++r) xs[r][j] = X[(r0 + r) * H_ + j];
    __syncthreads();
    const float* W = (m == 0) ? Wq : ((m == 1) ? Wk : Wv);
    float acc[RQ_];
    #pragma unroll
    for (int r = 0; r < RQ_; ++r) acc[r] = 0.f;
    #pragma unroll 8
    for (int i = 0; i < H_; ++i) {
        const float w = W[i * H_ + j];
        #pragma unroll
        for (int r = 0; r < RQ_; ++r) acc[r] += xs[r][i] * w;
    }
    const int h = j >> 6, d = j & 63;
    if (m == 0) {
        const float bj = bq[j];
        #pragma unroll
        for (int r = 0; r < RQ_; ++r) Q[(r0 + r) * H_ + j] = acc[r] + bj;
    } else if (m == 1) {
        const float bj = bk[j];
        #pragma unroll
        for (int r = 0; r < RQ_; ++r) {
            const int row = r0 + r, b = row / L_, l = row % L_;
            Kt[((b * NH_ + h) * HD_ + d) * LP_ + l] = acc[r] + bj + kpt[l * H_ + j];
        }
    } else {
        const float bj = bv[j];
        #pragma unroll
        for (int r = 0; r < RQ_; ++r) {
            const int row = r0 + r, b = row / L_, l = row % L_;
            Vp[((b * NH_ + h) * L_ + l) * HD_ + d] = acc[r] + bj + vpt[l * H_ + j];
        }
    }
}

// ------------------------------------------- fused attention + out-proj + LN
// grid = B * (L/4) = 400 blocks of 256 threads (4 waves).
// wave w: head h = w&1, q-pair qp = w>>1 -> q rows {q0+2qp, q0+2qp+1}.
__global__ __launch_bounds__(256)
void attn_out_kernel(const float* __restrict__ Q, const float* __restrict__ Kt,
                     const float* __restrict__ Vp, const int* __restrict__ tseq,
                     const float* __restrict__ mask,
                     const float* __restrict__ ktt, const float* __restrict__ vtt,
                     const float* __restrict__ Wd, const float* __restrict__ bd,
                     const float* __restrict__ X, const float* __restrict__ g,
                     const float* __restrict__ bb, float* __restrict__ out){
    const int b  = blockIdx.x / (L_ / 4);
    const int q0 = (blockIdx.x % (L_ / 4)) * 4;
    const int w  = threadIdx.x >> 6, lane = threadIdx.x & 63;
    const int h  = w & 1, qp = w >> 1;
    const int qa = q0 + 2 * qp, qb = qa + 1;
    const int bh = b * NH_ + h;

    __shared__ float ktt_s[TV_][H_ + 1];   // +1 pad: qkt access conflict-free
    __shared__ float vtt_s[TV_][H_ + 1];
    __shared__ __align__(16) float qs [4][2][HD_];
    __shared__ __align__(16) float qkt[4][2][TV_];
    __shared__ __align__(16) float ss [4][2][TV_];
    __shared__ __align__(16) float ps [4][2][LP_];
    __shared__ __align__(16) float ctx_s[4][H_];
    __shared__ float redA[4], redB[4], red2A[4], red2B[4];

    // coalesced table staging (16.5 KB x2)
    for (int t = threadIdx.x; t < TV_ * H_; t += 256) {
        ktt_s[t >> 7][t & 127] = ktt[t];
        vtt_s[t >> 7][t & 127] = vtt[t];
    }
    qs[w][0][lane] = Q[(b * L_ + qa) * H_ + h * HD_ + lane];
    qs[w][1][lane] = Q[(b * L_ + qb) * H_ + h * HD_ + lane];
    ss[w][lane >> 5][lane & 31] = 0.f;
    __syncthreads();

    // qkt[q][i] = dot(q_vec, ktt[i, head slice]); lane = (q-sel<<5)|bucket
    {
        const int i = lane & 31, qsel = lane >> 5;
        float a = 0.f;
        #pragma unroll 8
        for (int d = 0; d < HD_; ++d)
            a += qs[w][qsel][d] * ktt_s[i][h * HD_ + d];
        qkt[w][qsel][i] = a;
    }

    // ---- phase A: lane handles k = 4*lane .. 4*lane+3, for both q's
    const float4* kt4 = (const float4*)(Kt + (size_t)bh * HD_ * LP_);
    float4 sa = make_float4(0.f, 0.f, 0.f, 0.f);
    float4 sb = make_float4(0.f, 0.f, 0.f, 0.f);
    #pragma unroll 8
    for (int d = 0; d < HD_; ++d) {
        const float4 kv = kt4[d * (LP_ / 4) + lane];
        const float qad = qs[w][0][d], qbd = qs[w][1][d];
        sa.x += qad * kv.x; sa.y += qad * kv.y; sa.z += qad * kv.z; sa.w += qad * kv.w;
        sb.x += qbd * kv.x; sb.y += qbd * kv.y; sb.z += qbd * kv.z; sb.w += qbd * kv.w;
    }
    float sva[4] = {sa.x, sa.y, sa.z, sa.w};
    float svb[4] = {sb.x, sb.y, sb.z, sb.w};
    const int k0i = lane * 4;
    float mxa = -INFINITY, mxb = -INFINITY;
    if (k0i < L_) {  // lanes 0..49; rows 800B-aligned -> float4/int4 ok
        const float4 m4a = ((const float4*)(mask + ((size_t)(b * L_ + qa)) * L_))[lane];
        const float4 m4b = ((const float4*)(mask + ((size_t)(b * L_ + qb)) * L_))[lane];
        const int4   t4  = ((const int4*)(tseq + b * L_))[lane];
        const int    tqa = tseq[b * L_ + qa], tqb = tseq[b * L_ + qb];
        const float mva[4] = {m4a.x, m4a.y, m4a.z, m4a.w};
        const float mvb[4] = {m4b.x, m4b.y, m4b.z, m4b.w};
        const int   tk[4]  = {t4.x, t4.y, t4.z, t4.w};
        #pragma unroll
        for (int jj = 0; jj < 4; ++jj) {
            int dta = tqa - tk[jj]; if (dta < 0) dta = -dta;
            int dtb = tqb - tk[jj]; if (dtb < 0) dtb = -dtb;
            int ia = (int)log1pf((float)dta); if (ia > TV_ - 1) ia = TV_ - 1;
            int ib = (int)log1pf((float)dtb); if (ib > TV_ - 1) ib = TV_ - 1;
            float s_a = (sva[jj] + qkt[w][0][ia]) * 0.125f + mva[jj];
            float s_b = (svb[jj] + qkt[w][1][ib]) * 0.125f + mvb[jj];
            sva[jj] = s_a; svb[jj] = s_b;
            atomicAdd(&ss[w][0][ia], s_a);     // pre-softmax bucket sums
            atomicAdd(&ss[w][1][ib], s_b);
            if (s_a > mxa) mxa = s_a;
            if (s_b > mxb) mxb = s_b;
        }
    } else {
        sva[0] = sva[1] = sva[2] = sva[3] = -INFINITY;
        svb[0] = svb[1] = svb[2] = svb[3] = -INFINITY;
    }
    // wave-wide softmax (both q's)
    for (int off = 32; off; off >>= 1) {
        float oa = __shfl_xor(mxa, off); if (oa > mxa) mxa = oa;
        float ob = __shfl_xor(mxb, off); if (ob > mxb) mxb = ob;
    }
    float suma = 0.f, sumb = 0.f, eva[4], evb[4];
    #pragma unroll
    for (int jj = 0; jj < 4; ++jj) {
        float ea = (k0i + jj < L_) ? __expf(sva[jj] - mxa) : 0.f;
        float eb = (k0i + jj < L_) ? __expf(svb[jj] - mxb) : 0.f;
        eva[jj] = ea; suma += ea;
        evb[jj] = eb; sumb += eb;
    }
    for (int off = 32; off; off >>= 1) { suma += __shfl_xor(suma, off); sumb += __shfl_xor(sumb, off); }
    ((float4*)ps[w][0])[lane] = make_float4(eva[0], eva[1], eva[2], eva[3]);
    ((float4*)ps[w][1])[lane] = make_float4(evb[0], evb[1], evb[2], evb[3]);

    // ---- phase B: lane = d (ps/ss same-wave LDS, ordered)
    const float inva = 1.f / suma, invb = 1.f / sumb;
    const float* vp = Vp + (size_t)bh * L_ * HD_;
    const float4* psa4 = (const float4*)ps[w][0];
    const float4* psb4 = (const float4*)ps[w][1];
    float ca = 0.f, cb = 0.f;
    #pragma unroll 5
    for (int k4 = 0; k4 < L_ / 4; ++k4) {
        const float4 pa = psa4[k4], pb = psb4[k4];
        const int kb = k4 * 4;
        const float v0 = vp[(kb + 0) * HD_ + lane];
        const float v1 = vp[(kb + 1) * HD_ + lane];
        const float v2 = vp[(kb + 2) * HD_ + lane];
        const float v3 = vp[(kb + 3) * HD_ + lane];
        ca += pa.x * v0; ca += pa.y * v1; ca += pa.z * v2; ca += pa.w * v3;
        cb += pb.x * v0; cb += pb.y * v1; cb += pb.z * v2; cb += pb.w * v3;
    }
    ca *= inva; cb *= invb;
    float tca = 0.f, tcb = 0.f;
    const float4* ssa4 = (const float4*)ss[w][0];
    const float4* ssb4 = (const float4*)ss[w][1];
    #pragma unroll
    for (int i4 = 0; i4 < TV_ / 4; ++i4) {
        const float4 za = ssa4[i4], zb = ssb4[i4];
        const int i = i4 * 4;
        const float w0 = vtt_s[i + 0][h * HD_ + lane];
        const float w1 = vtt_s[i + 1][h * HD_ + lane];
        const float w2 = vtt_s[i + 2][h * HD_ + lane];
        const float w3 = vtt_s[i + 3][h * HD_ + lane];
        tca += za.x * w0; tca += za.y * w1; tca += za.z * w2; tca += za.w * w3;
        tcb += zb.x * w0; tcb += zb.y * w1; tcb += zb.z * w2; tcb += zb.w * w3;
    }
    ctx_s[2 * qp + 0][h * HD_ + lane] = ca + tca;
    ctx_s[2 * qp + 1][h * HD_ + lane] = cb + tcb;
    __syncthreads();

    // ---- out projection + residual + LayerNorm: 4 rows, 2 per thread
    const int r = threadIdx.x >> 7, j = threadIdx.x & 127;   // rows r and r+2
    const float4* ca4 = (const float4*)ctx_s[r];
    const float4* cb4 = (const float4*)ctx_s[r + 2];
    float acc_a = 0.f, acc_b = 0.f;
    #pragma unroll 8
    for (int i4 = 0; i4 < H_ / 4; ++i4) {
        const float4 xa = ca4[i4], xb = cb4[i4];
        const int i = i4 * 4;
        const float w0 = Wd[(i + 0) * H_ + j];
        const float w1 = Wd[(i + 1) * H_ + j];
        const float w2 = Wd[(i + 2) * H_ + j];
        const float w3 = Wd[(i + 3) * H_ + j];
        acc_a += xa.x * w0; acc_a += xa.y * w1; acc_a += xa.z * w2; acc_a += xa.w * w3;
        acc_b += xb.x * w0; acc_b += xb.y * w1; acc_b += xb.z * w2; acc_b += xb.w * w3;
    }
    const int rowa = b * L_ + q0 + r, rowb = rowa + 2;
    const float bdj = bd[j];
    const float x_a = acc_a + bdj + X[rowa * H_ + j];
    const float x_b = acc_b + bdj + X[rowb * H_ + j];

    float s1a = x_a, s1b = x_b;
    for (int off = 32; off; off >>= 1) { s1a += __shfl_xor(s1a, off); s1b += __shfl_xor(s1b, off); }
    if (lane == 0) { redA[w] = s1a; redB[w] = s1b; }
    __syncthreads();
    const float meanA = (redA[2 * r] + redA[2 * r + 1]) * (1.f / H_);
    const float meanB = (redB[2 * r] + redB[2 * r + 1]) * (1.f / H_);
    const float dxa = x_a - meanA, dxb = x_b - meanB;
    float s2a = dxa * dxa, s2b = dxb * dxb;
    for (int off = 32; off; off >>= 1) { s2a += __shfl_xor(s2a, off); s2b += __shfl_xor(s2b, off); }
    if (lane == 0) { red2A[w] = s2a; red2B[w] = s2b; }
    __syncthreads();
    const float varA = (red2A[2 * r] + red2A[2 * r + 1]) * (1.f / H_);
    const float varB = (red2B[2 * r] + red2B[2 * r + 1]) * (1.f / H_);
    const float gj = g[j], bbj = bb[j];
    out[rowa * H_ + j] = dxa * rsqrtf(varA + 1e-12f) * gj + bbj;
    out[rowb * H_ + j] = dxb * rsqrtf(varB + 1e-12f) * gj + bbj;
}

// ---------------------------------------------------------------- launch
extern "C" void kernel_launch(void* const* d_in, const int* in_sizes, int n_in,
                              void* d_out, int out_size, void* d_ws, size_t ws_size,
                              hipStream_t stream) {
    const float* X    = (const float*)d_in[0];
    const int*   tseq = (const int*)  d_in[1];
    const float* mask = (const float*)d_in[2];
    const float* Wq = (const float*)d_in[3],  *bq = (const float*)d_in[4];
    const float* Wk = (const float*)d_in[5],  *bk = (const float*)d_in[6];
    const float* Wv = (const float*)d_in[7],  *bv = (const float*)d_in[8];
    const float* Wd = (const float*)d_in[9],  *bd = (const float*)d_in[10];
    const float* g  = (const float*)d_in[11], *bb = (const float*)d_in[12];
    const float* ktt = (const float*)d_in[13], *vtt = (const float*)d_in[14];
    const float* kpt = (const float*)d_in[15], *vpt = (const float*)d_in[16];

    float* ws  = (float*)d_ws;
    float* Q   = ws;                          // B*L*H      = 204800
    float* Kt  = Q   + B_ * L_ * H_;          // B*NH*HD*LP = 262144 (pad unzeroed, by design)
    float* Vp  = Kt  + B_ * NH_ * HD_ * LP_;  // B*L*H      = 204800

    dim3 g1(B_ * L_ / RQ_, 3);
    qkv_kernel<<<g1, 128, 0, stream>>>(X, Wq, bq, Wk, bk, Wv, bv, kpt, vpt, Q, Kt, Vp);
    attn_out_kernel<<<B_ * (L_ / 4), 256, 0, stream>>>(Q, Kt, Vp, tseq, mask, ktt, vtt,
                                                       Wd, bd, X, g, bb, (float*)d_out);
}